// Round 23
// baseline (136.401 us; speedup 1.0000x reference)
//
#include <hip/hip_runtime.h>
#include <math.h>

#define BATCH 32
#define TLEN 8192
#define NQ 128           // quarters (serial producer units)
#define QLEN 64          // steps per quarter
#define SUBL 8           // steps per sub-chunk
#define NSUB8 8          // sub-chunks per quarter
#define NROWS (BATCH*TLEN)   // 262144 rows

typedef _Float16 h2 __attribute__((ext_vector_type(2)));
union HU { unsigned int u; h2 h; };
__device__ __forceinline__ h2 u2h(unsigned int x) { HU t; t.u = x; return t.h; }
__device__ __forceinline__ unsigned int h2u(h2 x) { HU t; t.h = x; return t.u; }
__device__ __forceinline__ unsigned int pkh(float a, float b) {
    HU t; t.h = h2{(_Float16)a, (_Float16)b}; return t.u;
}
__device__ __forceinline__ h2 splat(float a) {
    _Float16 v = (_Float16)a; return h2{v, v};
}

// ---------------------------------------------------------------------------
// HiPPO step, tree-form prefix: s <- (I - A/t) s + (x/t) * r
// ---------------------------------------------------------------------------
__device__ __forceinline__ void hippo_step(float s[8], float inv_t, float xb) {
    const float R[8] = {1.0f, 1.7320508075688772f, 2.23606797749979f,
                        2.6457513110645907f, 3.0f, 3.3166247903554f,
                        3.605551275463989f, 3.872983346207417f};
    float q0 = R[0]*s[0], q1 = R[1]*s[1], q2 = R[2]*s[2], q3 = R[3]*s[3];
    float q4 = R[4]*s[4], q5 = R[5]*s[5], q6 = R[6]*s[6];
    float t01 = q0+q1, t23 = q2+q3, t45 = q4+q5;
    float p1 = q0, p2 = t01, p3 = t01+q2, p4 = t01+t23;
    float p5 = p4+q4, p6 = p4+t45, p7 = p6+q6;
    float p[8] = {0.0f, p1, p2, p3, p4, p5, p6, p7};
    #pragma unroll
    for (int n = 0; n < 8; n++) {
        float as = fmaf(R[n], p[n], (float)(n + 1) * s[n]);
        s[n] = fmaf(-inv_t, as, fmaf(xb, R[n], s[n]));
    }
}

// ---------------------------------------------------------------------------
// Kernel 1: per-QUARTER runs (128 blocks x 64 serial steps, r16-proven shape).
// ---------------------------------------------------------------------------
__global__ void hippo_chunk_kernel(const float* __restrict__ x_seq,
                                   float* __restrict__ Psub,  // [NQ][8][8][8]
                                   float* __restrict__ Vsub,  // [NQ][8][64][8]
                                   float* __restrict__ Pq,    // [NQ][8][8]
                                   float* __restrict__ Vq)    // [NQ][64][8]
{
    int qidx = blockIdx.x;
    int tid = threadIdx.x;
    if (tid >= 72) return;
    bool isP = tid >= 64;
    int col = tid - 64;
    int b = tid >> 1, c = tid & 1;

    float s[8];
    #pragma unroll
    for (int n = 0; n < 8; n++) s[n] = (isP && n == col) ? 1.0f : 0.0f;

    int t0c = qidx * QLEN;
    size_t xbase = ((size_t)b * TLEN + t0c) * 2 + c;

    float xl[8];
    #pragma unroll
    for (int k = 0; k < 8; k++)
        xl[k] = isP ? 0.0f : x_seq[xbase + 2 * k];

    #pragma unroll 1
    for (int ii = 0; ii < QLEN; ii += 8) {
        int sub = ii >> 3;
        if (isP) {
            #pragma unroll
            for (int n = 0; n < 8; n++)
                Psub[(((size_t)qidx * NSUB8 + sub) * 8 + n) * 8 + col] = s[n];
        } else {
            #pragma unroll
            for (int n = 0; n < 8; n++)
                Vsub[(((size_t)qidx * NSUB8 + sub) * 64 + tid) * 8 + n] = s[n];
        }
        float xn8[8];
        bool more = (ii + 8 < QLEN) && !isP;
        #pragma unroll
        for (int k = 0; k < 8; k++)
            xn8[k] = more ? x_seq[xbase + 2 * (ii + 8 + k)] : 0.0f;

        #pragma unroll
        for (int k = 0; k < 8; k++) {
            float tf = (float)(t0c + ii + k + 1);
            float inv_t = 1.0f / tf;
            hippo_step(s, inv_t, xl[k] * inv_t);
        }
        #pragma unroll
        for (int k = 0; k < 8; k++) xl[k] = xn8[k];
    }
    if (isP) {
        #pragma unroll
        for (int n = 0; n < 8; n++) Pq[((size_t)qidx * 8 + n) * 8 + col] = s[n];
    } else {
        #pragma unroll
        for (int n = 0; n < 8; n++) Vq[((size_t)qidx * 64 + tid) * 8 + n] = s[n];
    }
}

// ---------------------------------------------------------------------------
// Kernel 2 (FUSED merge + compose, 1 block x 512 threads):
//  - stage all Pq to LDS (32 KB)
//  - merge each chunk's 4 quarters (V_c/P_c stay in LDS, Ppre/Vpre to global)
//  - 32-iteration chunk scan (r18/r20 structure) -> S0c
// Saves one launch gap + the V_c/P_c global round-trip vs r20-r22.
// ---------------------------------------------------------------------------
__global__ __launch_bounds__(512) void hippo_mc_kernel(
    const float* __restrict__ Pq,    // [NQ][8][8]
    const float* __restrict__ Vq,    // [NQ][64][8]
    float* __restrict__ Ppre,        // [32][3][8][8]
    float* __restrict__ Vpre,        // [32][3][64][8]
    float* __restrict__ S0c)         // [32][64][8]
{
    __shared__ float Pl[NQ * 64];    // 32 KB staged Pq
    __shared__ float Vcl[32 * 512];  // 64 KB chunk V summaries
    __shared__ float Pcl[32 * 64];   //  8 KB chunk P summaries
    __shared__ float sA[64 * 9], sB[64 * 9];
    __shared__ float pA[72], pB[72];
    int tid = threadIdx.x;           // (seq,n)
    int seq = tid >> 3, n = tid & 7;

    #pragma unroll 1
    for (int k = tid; k < NQ * 64; k += 512) Pl[k] = Pq[k];
    __syncthreads();

    // ---- merge phase: 32 chunks x 3 sub-steps
    #pragma unroll 1
    for (int c = 0; c < 32; c++) {
        float v0 = Vq[(size_t)(4 * c) * 512 + tid];
        sA[seq * 9 + n] = v0;
        Vpre[(size_t)(c * 3 + 0) * 512 + tid] = v0;
        if (tid < 64) {
            int nn = tid >> 3, mm = tid & 7;
            float p0 = Pl[(4 * c) * 64 + tid];
            pA[nn * 9 + mm] = p0;
            Ppre[(size_t)(c * 3 + 0) * 64 + tid] = p0;
        }
        __syncthreads();

        float* scur = sA; float* snxt = sB;
        float* pcur = pA; float* pnxt = pB;
        #pragma unroll
        for (int q = 1; q < 4; q++) {
            const float* Pg = &Pl[(4 * c + q) * 64];
            float acc = Vq[(size_t)(4 * c + q) * 512 + tid];
            #pragma unroll
            for (int m = 0; m < 8; m++)
                acc = fmaf(Pg[n * 8 + m], scur[seq * 9 + m], acc);
            snxt[seq * 9 + n] = acc;
            if (q < 3) Vpre[(size_t)(c * 3 + q) * 512 + tid] = acc;
            else       Vcl[c * 512 + tid] = acc;

            if (tid < 64) {
                int nn = tid >> 3, mm = tid & 7;
                float pa = 0.0f;
                #pragma unroll
                for (int k = 0; k < 8; k++)
                    pa = fmaf(Pg[nn * 8 + k], pcur[k * 9 + mm], pa);
                pnxt[nn * 9 + mm] = pa;
                if (q < 3) Ppre[(size_t)(c * 3 + q) * 64 + tid] = pa;
                else       Pcl[c * 64 + tid] = pa;
            }
            __syncthreads();
            float* t1 = scur; scur = snxt; snxt = t1;
            float* t2 = pcur; pcur = pnxt; pnxt = t2;
        }
    }

    // ---- scan phase: 32 iterations, pure LDS
    sA[seq * 9 + n] = 0.0f;
    __syncthreads();
    float* cur = sA; float* nxt = sB;
    #pragma unroll 1
    for (int ck = 0; ck < 32; ck++) {
        float sv = cur[seq * 9 + n];
        S0c[(size_t)ck * 512 + tid] = sv;
        float acc = Vcl[ck * 512 + tid];
        const float* Pr = &Pcl[ck * 64 + n * 8];
        const float* Sr = &cur[seq * 9];
        #pragma unroll
        for (int m = 0; m < 8; m++)
            acc = fmaf(Pr[m], Sr[m], acc);
        nxt[seq * 9 + n] = acc;
        __syncthreads();
        float* t = cur; cur = nxt; nxt = t;
    }
}

// ---------------------------------------------------------------------------
// KAN helpers
// ---------------------------------------------------------------------------
__device__ __forceinline__ void bspline4(float x, float& B0, float& B1,
                                         float& B2, float& B3, int& m)
{
    float tt = fmaf(x, 5.0f, 8.0f);        // (x + 1.6) * 5
    float fm = floorf(tt);
    float u = tt - fm;
    bool valid = (fm >= 0.0f) && (fm <= 15.0f);
    float u2 = u * u, u3 = u2 * u;
    float um = 1.0f - u;
    B0 = um * um * um * (1.0f / 6.0f);
    B3 = u3 * (1.0f / 6.0f);
    B1 = fmaf(3.0f, u3, fmaf(-6.0f, u2, 4.0f)) * (1.0f / 6.0f);
    B2 = fmaf(-3.0f, u3, fmaf(3.0f, u2, fmaf(3.0f, u, 1.0f))) * (1.0f / 6.0f);
    float msk = valid ? 1.0f : 0.0f;
    B0 *= msk; B1 *= msk; B2 *= msk; B3 *= msk;
    m = valid ? (int)fm : 0;
}

__device__ __forceinline__ float silu(float x) {
    return x / (1.0f + __expf(-x));
}

// FUSED EXPAND + KAN -- r21's proven optimum (74.4us): packed f16 o-pairs,
// weight LDS 20480 B, total 29696 B -> 4 blocks/CU (grid-capped 16 waves/CU,
// the hard ceiling at 1 row/thread). r22's dual-copy variant traded LDS size
// for occupancy and regressed; this layout stands.
__global__ __launch_bounds__(256) void kan_kernel(
    const float* __restrict__ x_seq,
    const float* __restrict__ Psub,
    const float* __restrict__ Vsub,
    const float* __restrict__ S0c,   // [32][64][8]
    const float* __restrict__ Ppre,  // [32][3][8][8]
    const float* __restrict__ Vpre,  // [32][3][64][8]
    const float* __restrict__ wb1, const float* __restrict__ ws1,
    const float* __restrict__ wb2, const float* __restrict__ ws2,
    const float* __restrict__ wb3, const float* __restrict__ ws3,
    float* __restrict__ out)
{
    __shared__ unsigned int wldsU[5120];     // 20480 B: wpk[4864] + wbpk[256]
    __shared__ unsigned int hbuf[256 * 9];   //  9216 B activations
    int tid = threadIdx.x;
    int b = blockIdx.x >> 5;                 // 0..31
    int tseg = blockIdx.x & 31;              // 0..31 == chunk
    int row = blockIdx.x * 256 + tid;
    int rot = ((tid >> 3) ^ (tid >> 6)) & 7;

    // ---- fused expand: 32 sub-chunks x 2 c -> hbuf rows
    if (tid < 64) {
        int uc = tid >> 1;                   // 0..31
        int c = tid & 1;
        int q = uc >> 3;                     // quarter within chunk 0..3
        int qidx = tseg * 4 + q;
        int sub8 = uc & 7;
        int seq = b * 2 + c;
        int row_loc = uc << 3;
        int wrot = (uc ^ (uc >> 3)) & 7;

        float sc[8];
        #pragma unroll
        for (int n = 0; n < 8; n++)
            sc[n] = S0c[((size_t)tseg * 64 + seq) * 8 + n];

        float s0v[8];
        if (q == 0) {
            #pragma unroll
            for (int n = 0; n < 8; n++) s0v[n] = sc[n];
        } else {
            const float* Pp2 = &Ppre[(size_t)(tseg * 3 + q - 1) * 64];
            const float* Vp2 = &Vpre[((size_t)(tseg * 3 + q - 1) * 64 + seq) * 8];
            #pragma unroll
            for (int n = 0; n < 8; n++) {
                float acc = Vp2[n];
                #pragma unroll
                for (int m = 0; m < 8; m++)
                    acc = fmaf(Pp2[n * 8 + m], sc[m], acc);
                s0v[n] = acc;
            }
        }

        const float* Pp = &Psub[((size_t)qidx * NSUB8 + sub8) * 64];
        const float* Vp = &Vsub[(((size_t)qidx * NSUB8 + sub8) * 64 + seq) * 8];

        float s[8];
        #pragma unroll
        for (int n = 0; n < 8; n++) {
            float acc = Vp[n];
            #pragma unroll
            for (int m = 0; m < 8; m++)
                acc = fmaf(Pp[n * 8 + m], s0v[m], acc);
            s[n] = acc;
        }

        int t0 = qidx * QLEN + sub8 * SUBL;  // == tseg*256 + uc*8
        float xv8[8];
        #pragma unroll
        for (int k = 0; k < 8; k++)
            xv8[k] = x_seq[((size_t)b * TLEN + t0 + k) * 2 + c];

        #pragma unroll
        for (int i = 0; i < SUBL; i++) {
            float tf = (float)(t0 + i + 1);
            float inv_t = 1.0f / tf;
            hippo_step(s, inv_t, xv8[i] * inv_t);
            #pragma unroll
            for (int k = 0; k < 4; k++)
                hbuf[(row_loc + i) * 9 + ((c * 4 + k + wrot) & 7)] =
                    pkh(s[2 * k], s[2 * k + 1]);
        }
    }

    // ---- stage phase 1: wpk1[i<16][o2<16][19] + wbpk1[256]  (1 edge/thread)
    {
        int i = tid >> 4, o2 = tid & 15;
        int o0 = 2 * o2, o1 = o0 + 1;
        const float* s0 = ws1 + o0 * 208 + i * 13;
        const float* s1 = ws1 + o1 * 208 + i * 13;
        int dst = i * 304 + o2 * 19;
        #pragma unroll
        for (int j = 0; j < 19; j++) {
            bool v = (j >= 3 && j <= 15);
            float lo = v ? s0[j - 3] : 0.0f;
            float hi = v ? s1[j - 3] : 0.0f;
            wldsU[dst + j] = pkh(lo, hi);
        }
        wldsU[4864 + tid] = pkh(wb1[o0 * 16 + i], wb1[o1 * 16 + i]);
    }
    __syncthreads();

    // ---- layer 1: 16 -> 32, packed o-pairs
    h2 acc1p[16];
    #pragma unroll
    for (int o = 0; o < 16; o++) acc1p[o] = h2{(_Float16)0.0f, (_Float16)0.0f};

    #pragma unroll 1
    for (int pi = 0; pi < 8; pi++) {
        h2 xp = u2h(hbuf[tid * 9 + ((pi + rot) & 7)]);
        #pragma unroll
        for (int par = 0; par < 2; par++) {
            int i = 2 * pi + par;
            float xv = (par == 0) ? (float)xp.x : (float)xp.y;
            float sx = silu(xv);
            float B0, B1, B2, B3; int m;
            bspline4(xv, B0, B1, B2, B3, m);
            h2 B0p = splat(B0), B1p = splat(B1), B2p = splat(B2), B3p = splat(B3);
            h2 sxp = splat(sx);
            int base = i * 304 + m;
            #pragma unroll
            for (int o2 = 0; o2 < 16; o2++) {
                int a0 = base + o2 * 19;
                unsigned int d0 = wldsU[a0];
                unsigned int d1 = wldsU[a0 + 1];
                unsigned int d2 = wldsU[a0 + 2];
                unsigned int d3 = wldsU[a0 + 3];
                h2 a = acc1p[o2];
                a = B0p * u2h(d0) + a;
                a = B1p * u2h(d1) + a;
                a = B2p * u2h(d2) + a;
                a = B3p * u2h(d3) + a;
                a = sxp * u2h(wldsU[4864 + i * 16 + o2]) + a;
                acc1p[o2] = a;
            }
        }
    }
    // first half of layer-1 output (pairs 0..7 = outputs 0..15) -> own row
    #pragma unroll
    for (int op = 0; op < 8; op++)
        hbuf[tid * 9 + ((op + rot) & 7)] = h2u(acc1p[op]);

    __syncthreads();   // all waves done reading phase-1 weights

    // ---- stage phase 2: wpk2[i<32][o2<8][19] + wbpk2[256]  (1 edge/thread)
    {
        int i = tid >> 3, o2 = tid & 7;
        int o0 = 2 * o2, o1 = o0 + 1;
        const float* s0 = ws2 + o0 * 416 + i * 13;
        const float* s1 = ws2 + o1 * 416 + i * 13;
        int dst = i * 152 + o2 * 19;
        #pragma unroll
        for (int j = 0; j < 19; j++) {
            bool v = (j >= 3 && j <= 15);
            float lo = v ? s0[j - 3] : 0.0f;
            float hi = v ? s1[j - 3] : 0.0f;
            wldsU[dst + j] = pkh(lo, hi);
        }
        wldsU[4864 + tid] = pkh(wb2[o0 * 32 + i], wb2[o1 * 32 + i]);
    }
    __syncthreads();

    // ---- layer 2: 32 -> 16 in two input halves, packed o-pairs
    h2 acc2p[8];
    #pragma unroll
    for (int o = 0; o < 8; o++) acc2p[o] = h2{(_Float16)0.0f, (_Float16)0.0f};

    #pragma unroll 1
    for (int half = 0; half < 2; half++) {
        #pragma unroll 1
        for (int pi = 0; pi < 8; pi++) {
            h2 yp = u2h(hbuf[tid * 9 + ((pi + rot) & 7)]);
            #pragma unroll
            for (int par = 0; par < 2; par++) {
                int i = half * 16 + 2 * pi + par;
                float yv = (par == 0) ? (float)yp.x : (float)yp.y;
                float sx = silu(yv);
                float B0, B1, B2, B3; int m;
                bspline4(yv, B0, B1, B2, B3, m);
                h2 B0p = splat(B0), B1p = splat(B1), B2p = splat(B2), B3p = splat(B3);
                h2 sxp = splat(sx);
                int base = i * 152 + m;
                #pragma unroll
                for (int o2 = 0; o2 < 8; o2++) {
                    int a0 = base + o2 * 19;
                    unsigned int d0 = wldsU[a0];
                    unsigned int d1 = wldsU[a0 + 1];
                    unsigned int d2 = wldsU[a0 + 2];
                    unsigned int d3 = wldsU[a0 + 3];
                    h2 a = acc2p[o2];
                    a = B0p * u2h(d0) + a;
                    a = B1p * u2h(d1) + a;
                    a = B2p * u2h(d2) + a;
                    a = B3p * u2h(d3) + a;
                    a = sxp * u2h(wldsU[4864 + i * 8 + o2]) + a;
                    acc2p[o2] = a;
                }
            }
        }
        if (half == 0) {
            // second half of layer-1 output (pairs 8..15) -> own row
            #pragma unroll
            for (int op = 0; op < 8; op++)
                hbuf[tid * 9 + ((op + rot) & 7)] = h2u(acc1p[8 + op]);
        }
    }

    // ---- layer 3: 16 -> 1, fully unrolled, fp32 weights from global
    float acc3 = 0.0f;
    #pragma unroll
    for (int i = 0; i < 16; i++) {
        h2 pr = acc2p[i >> 1];
        float xv = (i & 1) ? (float)pr.y : (float)pr.x;
        float sx = silu(xv);
        float B0, B1, B2, B3; int m;
        bspline4(xv, B0, B1, B2, B3, m);
        acc3 = fmaf(sx, wb3[i], acc3);
        const float* w3 = &ws3[i * 13];
        int j0 = m - 3;
        float w0v = (j0 >= 0)              ? w3[j0]     : 0.0f;
        float w1v = (j0 >= -1 && j0 <= 11) ? w3[j0 + 1] : 0.0f;
        float w2v = (j0 >= -2 && j0 <= 10) ? w3[j0 + 2] : 0.0f;
        float w3v = (j0 <= 9)              ? w3[j0 + 3] : 0.0f;
        acc3 = fmaf(B0, w0v, acc3);
        acc3 = fmaf(B1, w1v, acc3);
        acc3 = fmaf(B2, w2v, acc3);
        acc3 = fmaf(B3, w3v, acc3);
    }
    out[row] = acc3;
}

// ---------------------------------------------------------------------------
extern "C" void kernel_launch(void* const* d_in, const int* in_sizes, int n_in,
                              void* d_out, int out_size, void* d_ws, size_t ws_size,
                              hipStream_t stream) {
    const float* x_seq = (const float*)d_in[0];
    const float* wb1   = (const float*)d_in[1];
    const float* ws1   = (const float*)d_in[2];
    const float* wb2   = (const float*)d_in[3];
    const float* ws2   = (const float*)d_in[4];
    const float* wb3   = (const float*)d_in[5];
    const float* ws3   = (const float*)d_in[6];

    float* ws   = (float*)d_ws;
    float* Psub = ws;                   // 128*8*64        =   65536
    float* Vsub = ws + 65536;           // 128*8*64*8      =  524288
    float* Pq   = ws + 589824;          // 128*64          =    8192
    float* Vq   = ws + 598016;          // 128*512         =   65536
    float* Ppre = ws + 663552;          // 32*3*64         =    6144
    float* Vpre = ws + 669696;          // 32*3*512        =   49152
    float* S0c  = ws + 718848;          // 32*512          =   16384
    float* out  = (float*)d_out;

    hipLaunchKernelGGL(hippo_chunk_kernel, dim3(NQ), dim3(128), 0, stream,
                       x_seq, Psub, Vsub, Pq, Vq);
    hipLaunchKernelGGL(hippo_mc_kernel,    dim3(1),  dim3(512), 0, stream,
                       Pq, Vq, Ppre, Vpre, S0c);
    hipLaunchKernelGGL(kan_kernel, dim3(NROWS / 256), dim3(256), 0, stream,
                       x_seq, Psub, Vsub, S0c, Ppre, Vpre,
                       wb1, ws1, wb2, ws2, wb3, ws3, out);
}

// Round 24
// 94.017 us; speedup vs baseline: 1.4508x; 1.4508x over previous
//
#include <hip/hip_runtime.h>
#include <math.h>

#define BATCH 32
#define TLEN 8192
#define NQ 128           // quarters (serial producer units)
#define QLEN 64          // steps per quarter
#define SUBL 8           // steps per sub-chunk
#define NSUB8 8          // sub-chunks per quarter
#define NROWS (BATCH*TLEN)   // 262144 rows

typedef _Float16 h2 __attribute__((ext_vector_type(2)));
union HU { unsigned int u; h2 h; };
__device__ __forceinline__ h2 u2h(unsigned int x) { HU t; t.u = x; return t.h; }
__device__ __forceinline__ unsigned int h2u(h2 x) { HU t; t.h = x; return t.u; }
__device__ __forceinline__ unsigned int pkh(float a, float b) {
    HU t; t.h = h2{(_Float16)a, (_Float16)b}; return t.u;
}
__device__ __forceinline__ h2 splat(float a) {
    _Float16 v = (_Float16)a; return h2{v, v};
}

// ---------------------------------------------------------------------------
// HiPPO step, tree-form prefix: s <- (I - A/t) s + (x/t) * r
// ---------------------------------------------------------------------------
__device__ __forceinline__ void hippo_step(float s[8], float inv_t, float xb) {
    const float R[8] = {1.0f, 1.7320508075688772f, 2.23606797749979f,
                        2.6457513110645907f, 3.0f, 3.3166247903554f,
                        3.605551275463989f, 3.872983346207417f};
    float q0 = R[0]*s[0], q1 = R[1]*s[1], q2 = R[2]*s[2], q3 = R[3]*s[3];
    float q4 = R[4]*s[4], q5 = R[5]*s[5], q6 = R[6]*s[6];
    float t01 = q0+q1, t23 = q2+q3, t45 = q4+q5;
    float p1 = q0, p2 = t01, p3 = t01+q2, p4 = t01+t23;
    float p5 = p4+q4, p6 = p4+t45, p7 = p6+q6;
    float p[8] = {0.0f, p1, p2, p3, p4, p5, p6, p7};
    #pragma unroll
    for (int n = 0; n < 8; n++) {
        float as = fmaf(R[n], p[n], (float)(n + 1) * s[n]);
        s[n] = fmaf(-inv_t, as, fmaf(xb, R[n], s[n]));
    }
}

// ---------------------------------------------------------------------------
// Kernel 1: per-QUARTER runs (128 blocks x 64 serial steps, r16-proven shape).
// ---------------------------------------------------------------------------
__global__ void hippo_chunk_kernel(const float* __restrict__ x_seq,
                                   float* __restrict__ Psub,  // [NQ][8][8][8]
                                   float* __restrict__ Vsub,  // [NQ][8][64][8]
                                   float* __restrict__ Pq,    // [NQ][8][8]
                                   float* __restrict__ Vq)    // [NQ][64][8]
{
    int qidx = blockIdx.x;
    int tid = threadIdx.x;
    if (tid >= 72) return;
    bool isP = tid >= 64;
    int col = tid - 64;
    int b = tid >> 1, c = tid & 1;

    float s[8];
    #pragma unroll
    for (int n = 0; n < 8; n++) s[n] = (isP && n == col) ? 1.0f : 0.0f;

    int t0c = qidx * QLEN;
    size_t xbase = ((size_t)b * TLEN + t0c) * 2 + c;

    float xl[8];
    #pragma unroll
    for (int k = 0; k < 8; k++)
        xl[k] = isP ? 0.0f : x_seq[xbase + 2 * k];

    #pragma unroll 1
    for (int ii = 0; ii < QLEN; ii += 8) {
        int sub = ii >> 3;
        if (isP) {
            #pragma unroll
            for (int n = 0; n < 8; n++)
                Psub[(((size_t)qidx * NSUB8 + sub) * 8 + n) * 8 + col] = s[n];
        } else {
            #pragma unroll
            for (int n = 0; n < 8; n++)
                Vsub[(((size_t)qidx * NSUB8 + sub) * 64 + tid) * 8 + n] = s[n];
        }
        float xn8[8];
        bool more = (ii + 8 < QLEN) && !isP;
        #pragma unroll
        for (int k = 0; k < 8; k++)
            xn8[k] = more ? x_seq[xbase + 2 * (ii + 8 + k)] : 0.0f;

        #pragma unroll
        for (int k = 0; k < 8; k++) {
            float tf = (float)(t0c + ii + k + 1);
            float inv_t = 1.0f / tf;
            hippo_step(s, inv_t, xl[k] * inv_t);
        }
        #pragma unroll
        for (int k = 0; k < 8; k++) xl[k] = xn8[k];
    }
    if (isP) {
        #pragma unroll
        for (int n = 0; n < 8; n++) Pq[((size_t)qidx * 8 + n) * 8 + col] = s[n];
    } else {
        #pragma unroll
        for (int n = 0; n < 8; n++) Vq[((size_t)qidx * 64 + tid) * 8 + n] = s[n];
    }
}

// ---------------------------------------------------------------------------
// Kernel 2: merge 4 quarters -> chunk summaries + intra-chunk prefixes.
// 32 PARALLEL blocks (r23 lesson: serializing this on 1 block cost ~40us).
// ---------------------------------------------------------------------------
__global__ __launch_bounds__(512) void hippo_merge_kernel(
    const float* __restrict__ Pq,    // [NQ][8][8]
    const float* __restrict__ Vq,    // [NQ][64][8]
    float* __restrict__ P_c,         // [32][8][8]
    float* __restrict__ V_c,         // [32][64][8]
    float* __restrict__ Ppre,        // [32][3][8][8]
    float* __restrict__ Vpre)        // [32][3][64][8]
{
    __shared__ float stA[64 * 9], stB[64 * 9];
    __shared__ float PA[72], PB[72];
    int c = blockIdx.x;
    int tid = threadIdx.x;           // (seq,n)
    int seq = tid >> 3, n = tid & 7;

    float v0 = Vq[(size_t)(4 * c) * 512 + tid];
    stA[seq * 9 + n] = v0;
    Vpre[((size_t)(c * 3 + 0) * 64 + seq) * 8 + n] = v0;
    if (tid < 64) {
        int nn = tid >> 3, mm = tid & 7;
        float p0 = Pq[(size_t)(4 * c) * 64 + nn * 8 + mm];
        PA[nn * 9 + mm] = p0;
        Ppre[((size_t)(c * 3 + 0) * 8 + nn) * 8 + mm] = p0;
    }
    __syncthreads();

    float* scur = stA; float* snxt = stB;
    float* pcur = PA;  float* pnxt = PB;
    #pragma unroll
    for (int q = 1; q < 4; q++) {
        const float* Pg = &Pq[(size_t)(4 * c + q) * 64];
        float acc = Vq[(size_t)(4 * c + q) * 512 + tid];
        #pragma unroll
        for (int m = 0; m < 8; m++)
            acc = fmaf(Pg[n * 8 + m], scur[seq * 9 + m], acc);
        snxt[seq * 9 + n] = acc;
        if (q < 3) Vpre[((size_t)(c * 3 + q) * 64 + seq) * 8 + n] = acc;
        else       V_c[(size_t)c * 512 + tid] = acc;

        if (tid < 64) {
            int nn = tid >> 3, mm = tid & 7;
            float pa = 0.0f;
            #pragma unroll
            for (int k = 0; k < 8; k++)
                pa = fmaf(Pg[nn * 8 + k], pcur[k * 9 + mm], pa);
            pnxt[nn * 9 + mm] = pa;
            if (q < 3) Ppre[((size_t)(c * 3 + q) * 8 + nn) * 8 + mm] = pa;
            else       P_c[(size_t)c * 64 + nn * 8 + mm] = pa;
        }
        __syncthreads();
        float* t1 = scur; scur = snxt; snxt = t1;
        float* t2 = pcur; pcur = pnxt; pnxt = t2;
    }
}

// ---------------------------------------------------------------------------
// Kernel 3: chunk-level scan, pure LDS (r18/r20-proven), emits S0c only.
// ---------------------------------------------------------------------------
__global__ __launch_bounds__(512) void hippo_compose_kernel(
    const float* __restrict__ P_c,   // [32][8][8]
    const float* __restrict__ V_c,   // [32][64][8]
    float* __restrict__ S0c)         // [32][64][8]
{
    __shared__ float Pl[32 * 64];    //  8 KB
    __shared__ float Vl[32 * 512];   // 64 KB
    __shared__ float sA[64 * 9], sB[64 * 9];
    int tid = threadIdx.x;           // (seq,n)
    int seq = tid >> 3, n = tid & 7;

    #pragma unroll 1
    for (int k = tid; k < 32 * 64; k += 512) Pl[k] = P_c[k];
    {
        const float4* v4 = (const float4*)V_c;
        float4* l4 = (float4*)Vl;
        #pragma unroll 1
        for (int k = tid; k < 32 * 128; k += 512) l4[k] = v4[k];
    }
    sA[seq * 9 + n] = 0.0f;
    __syncthreads();

    float* cur = sA; float* nxt = sB;
    #pragma unroll 1
    for (int ck = 0; ck < 32; ck++) {
        float sv = cur[seq * 9 + n];
        S0c[(size_t)ck * 512 + tid] = sv;
        float acc = Vl[ck * 512 + tid];
        const float* Pr = &Pl[ck * 64 + n * 8];
        const float* Sr = &cur[seq * 9];
        #pragma unroll
        for (int m = 0; m < 8; m++)
            acc = fmaf(Pr[m], Sr[m], acc);
        nxt[seq * 9 + n] = acc;
        __syncthreads();
        float* t = cur; cur = nxt; nxt = t;
    }
}

// ---------------------------------------------------------------------------
// KAN helpers
// ---------------------------------------------------------------------------
__device__ __forceinline__ void bspline4(float x, float& B0, float& B1,
                                         float& B2, float& B3, int& m)
{
    float tt = fmaf(x, 5.0f, 8.0f);        // (x + 1.6) * 5
    float fm = floorf(tt);
    float u = tt - fm;
    bool valid = (fm >= 0.0f) && (fm <= 15.0f);
    float u2 = u * u, u3 = u2 * u;
    float um = 1.0f - u;
    B0 = um * um * um * (1.0f / 6.0f);
    B3 = u3 * (1.0f / 6.0f);
    B1 = fmaf(3.0f, u3, fmaf(-6.0f, u2, 4.0f)) * (1.0f / 6.0f);
    B2 = fmaf(-3.0f, u3, fmaf(3.0f, u2, fmaf(3.0f, u, 1.0f))) * (1.0f / 6.0f);
    float msk = valid ? 1.0f : 0.0f;
    B0 *= msk; B1 *= msk; B2 *= msk; B3 *= msk;
    m = valid ? (int)fm : 0;
}

__device__ __forceinline__ float silu(float x) {
    return x / (1.0f + __expf(-x));
}

// FUSED EXPAND + KAN -- r21's proven optimum (74.4us): packed f16 o-pairs,
// weight LDS 20480 B, total 29696 B -> 4 blocks/CU (grid-capped 16 waves/CU,
// the hard ceiling at 1 row/thread).
__global__ __launch_bounds__(256) void kan_kernel(
    const float* __restrict__ x_seq,
    const float* __restrict__ Psub,
    const float* __restrict__ Vsub,
    const float* __restrict__ S0c,   // [32][64][8]
    const float* __restrict__ Ppre,  // [32][3][8][8]
    const float* __restrict__ Vpre,  // [32][3][64][8]
    const float* __restrict__ wb1, const float* __restrict__ ws1,
    const float* __restrict__ wb2, const float* __restrict__ ws2,
    const float* __restrict__ wb3, const float* __restrict__ ws3,
    float* __restrict__ out)
{
    __shared__ unsigned int wldsU[5120];     // 20480 B: wpk[4864] + wbpk[256]
    __shared__ unsigned int hbuf[256 * 9];   //  9216 B activations
    int tid = threadIdx.x;
    int b = blockIdx.x >> 5;                 // 0..31
    int tseg = blockIdx.x & 31;              // 0..31 == chunk
    int row = blockIdx.x * 256 + tid;
    int rot = ((tid >> 3) ^ (tid >> 6)) & 7;

    // ---- fused expand: 32 sub-chunks x 2 c -> hbuf rows
    if (tid < 64) {
        int uc = tid >> 1;                   // 0..31
        int c = tid & 1;
        int q = uc >> 3;                     // quarter within chunk 0..3
        int qidx = tseg * 4 + q;
        int sub8 = uc & 7;
        int seq = b * 2 + c;
        int row_loc = uc << 3;
        int wrot = (uc ^ (uc >> 3)) & 7;

        float sc[8];
        #pragma unroll
        for (int n = 0; n < 8; n++)
            sc[n] = S0c[((size_t)tseg * 64 + seq) * 8 + n];

        float s0v[8];
        if (q == 0) {
            #pragma unroll
            for (int n = 0; n < 8; n++) s0v[n] = sc[n];
        } else {
            const float* Pp2 = &Ppre[(size_t)(tseg * 3 + q - 1) * 64];
            const float* Vp2 = &Vpre[((size_t)(tseg * 3 + q - 1) * 64 + seq) * 8];
            #pragma unroll
            for (int n = 0; n < 8; n++) {
                float acc = Vp2[n];
                #pragma unroll
                for (int m = 0; m < 8; m++)
                    acc = fmaf(Pp2[n * 8 + m], sc[m], acc);
                s0v[n] = acc;
            }
        }

        const float* Pp = &Psub[((size_t)qidx * NSUB8 + sub8) * 64];
        const float* Vp = &Vsub[(((size_t)qidx * NSUB8 + sub8) * 64 + seq) * 8];

        float s[8];
        #pragma unroll
        for (int n = 0; n < 8; n++) {
            float acc = Vp[n];
            #pragma unroll
            for (int m = 0; m < 8; m++)
                acc = fmaf(Pp[n * 8 + m], s0v[m], acc);
            s[n] = acc;
        }

        int t0 = qidx * QLEN + sub8 * SUBL;  // == tseg*256 + uc*8
        float xv8[8];
        #pragma unroll
        for (int k = 0; k < 8; k++)
            xv8[k] = x_seq[((size_t)b * TLEN + t0 + k) * 2 + c];

        #pragma unroll
        for (int i = 0; i < SUBL; i++) {
            float tf = (float)(t0 + i + 1);
            float inv_t = 1.0f / tf;
            hippo_step(s, inv_t, xv8[i] * inv_t);
            #pragma unroll
            for (int k = 0; k < 4; k++)
                hbuf[(row_loc + i) * 9 + ((c * 4 + k + wrot) & 7)] =
                    pkh(s[2 * k], s[2 * k + 1]);
        }
    }

    // ---- stage phase 1: wpk1[i<16][o2<16][19] + wbpk1[256]  (1 edge/thread)
    {
        int i = tid >> 4, o2 = tid & 15;
        int o0 = 2 * o2, o1 = o0 + 1;
        const float* s0 = ws1 + o0 * 208 + i * 13;
        const float* s1 = ws1 + o1 * 208 + i * 13;
        int dst = i * 304 + o2 * 19;
        #pragma unroll
        for (int j = 0; j < 19; j++) {
            bool v = (j >= 3 && j <= 15);
            float lo = v ? s0[j - 3] : 0.0f;
            float hi = v ? s1[j - 3] : 0.0f;
            wldsU[dst + j] = pkh(lo, hi);
        }
        wldsU[4864 + tid] = pkh(wb1[o0 * 16 + i], wb1[o1 * 16 + i]);
    }
    __syncthreads();

    // ---- layer 1: 16 -> 32, packed o-pairs
    h2 acc1p[16];
    #pragma unroll
    for (int o = 0; o < 16; o++) acc1p[o] = h2{(_Float16)0.0f, (_Float16)0.0f};

    #pragma unroll 1
    for (int pi = 0; pi < 8; pi++) {
        h2 xp = u2h(hbuf[tid * 9 + ((pi + rot) & 7)]);
        #pragma unroll
        for (int par = 0; par < 2; par++) {
            int i = 2 * pi + par;
            float xv = (par == 0) ? (float)xp.x : (float)xp.y;
            float sx = silu(xv);
            float B0, B1, B2, B3; int m;
            bspline4(xv, B0, B1, B2, B3, m);
            h2 B0p = splat(B0), B1p = splat(B1), B2p = splat(B2), B3p = splat(B3);
            h2 sxp = splat(sx);
            int base = i * 304 + m;
            #pragma unroll
            for (int o2 = 0; o2 < 16; o2++) {
                int a0 = base + o2 * 19;
                unsigned int d0 = wldsU[a0];
                unsigned int d1 = wldsU[a0 + 1];
                unsigned int d2 = wldsU[a0 + 2];
                unsigned int d3 = wldsU[a0 + 3];
                h2 a = acc1p[o2];
                a = B0p * u2h(d0) + a;
                a = B1p * u2h(d1) + a;
                a = B2p * u2h(d2) + a;
                a = B3p * u2h(d3) + a;
                a = sxp * u2h(wldsU[4864 + i * 16 + o2]) + a;
                acc1p[o2] = a;
            }
        }
    }
    // first half of layer-1 output (pairs 0..7 = outputs 0..15) -> own row
    #pragma unroll
    for (int op = 0; op < 8; op++)
        hbuf[tid * 9 + ((op + rot) & 7)] = h2u(acc1p[op]);

    __syncthreads();   // all waves done reading phase-1 weights

    // ---- stage phase 2: wpk2[i<32][o2<8][19] + wbpk2[256]  (1 edge/thread)
    {
        int i = tid >> 3, o2 = tid & 7;
        int o0 = 2 * o2, o1 = o0 + 1;
        const float* s0 = ws2 + o0 * 416 + i * 13;
        const float* s1 = ws2 + o1 * 416 + i * 13;
        int dst = i * 152 + o2 * 19;
        #pragma unroll
        for (int j = 0; j < 19; j++) {
            bool v = (j >= 3 && j <= 15);
            float lo = v ? s0[j - 3] : 0.0f;
            float hi = v ? s1[j - 3] : 0.0f;
            wldsU[dst + j] = pkh(lo, hi);
        }
        wldsU[4864 + tid] = pkh(wb2[o0 * 32 + i], wb2[o1 * 32 + i]);
    }
    __syncthreads();

    // ---- layer 2: 32 -> 16 in two input halves, packed o-pairs
    h2 acc2p[8];
    #pragma unroll
    for (int o = 0; o < 8; o++) acc2p[o] = h2{(_Float16)0.0f, (_Float16)0.0f};

    #pragma unroll 1
    for (int half = 0; half < 2; half++) {
        #pragma unroll 1
        for (int pi = 0; pi < 8; pi++) {
            h2 yp = u2h(hbuf[tid * 9 + ((pi + rot) & 7)]);
            #pragma unroll
            for (int par = 0; par < 2; par++) {
                int i = half * 16 + 2 * pi + par;
                float yv = (par == 0) ? (float)yp.x : (float)yp.y;
                float sx = silu(yv);
                float B0, B1, B2, B3; int m;
                bspline4(yv, B0, B1, B2, B3, m);
                h2 B0p = splat(B0), B1p = splat(B1), B2p = splat(B2), B3p = splat(B3);
                h2 sxp = splat(sx);
                int base = i * 152 + m;
                #pragma unroll
                for (int o2 = 0; o2 < 8; o2++) {
                    int a0 = base + o2 * 19;
                    unsigned int d0 = wldsU[a0];
                    unsigned int d1 = wldsU[a0 + 1];
                    unsigned int d2 = wldsU[a0 + 2];
                    unsigned int d3 = wldsU[a0 + 3];
                    h2 a = acc2p[o2];
                    a = B0p * u2h(d0) + a;
                    a = B1p * u2h(d1) + a;
                    a = B2p * u2h(d2) + a;
                    a = B3p * u2h(d3) + a;
                    a = sxp * u2h(wldsU[4864 + i * 8 + o2]) + a;
                    acc2p[o2] = a;
                }
            }
        }
        if (half == 0) {
            // second half of layer-1 output (pairs 8..15) -> own row
            #pragma unroll
            for (int op = 0; op < 8; op++)
                hbuf[tid * 9 + ((op + rot) & 7)] = h2u(acc1p[8 + op]);
        }
    }

    // ---- layer 3: 16 -> 1, fully unrolled, fp32 weights from global
    float acc3 = 0.0f;
    #pragma unroll
    for (int i = 0; i < 16; i++) {
        h2 pr = acc2p[i >> 1];
        float xv = (i & 1) ? (float)pr.y : (float)pr.x;
        float sx = silu(xv);
        float B0, B1, B2, B3; int m;
        bspline4(xv, B0, B1, B2, B3, m);
        acc3 = fmaf(sx, wb3[i], acc3);
        const float* w3 = &ws3[i * 13];
        int j0 = m - 3;
        float w0v = (j0 >= 0)              ? w3[j0]     : 0.0f;
        float w1v = (j0 >= -1 && j0 <= 11) ? w3[j0 + 1] : 0.0f;
        float w2v = (j0 >= -2 && j0 <= 10) ? w3[j0 + 2] : 0.0f;
        float w3v = (j0 <= 9)              ? w3[j0 + 3] : 0.0f;
        acc3 = fmaf(B0, w0v, acc3);
        acc3 = fmaf(B1, w1v, acc3);
        acc3 = fmaf(B2, w2v, acc3);
        acc3 = fmaf(B3, w3v, acc3);
    }
    out[row] = acc3;
}

// ---------------------------------------------------------------------------
extern "C" void kernel_launch(void* const* d_in, const int* in_sizes, int n_in,
                              void* d_out, int out_size, void* d_ws, size_t ws_size,
                              hipStream_t stream) {
    const float* x_seq = (const float*)d_in[0];
    const float* wb1   = (const float*)d_in[1];
    const float* ws1   = (const float*)d_in[2];
    const float* wb2   = (const float*)d_in[3];
    const float* ws2   = (const float*)d_in[4];
    const float* wb3   = (const float*)d_in[5];
    const float* ws3   = (const float*)d_in[6];

    float* ws   = (float*)d_ws;
    float* Psub = ws;                   // 128*8*64        =   65536
    float* Vsub = ws + 65536;           // 128*8*64*8      =  524288
    float* Pq   = ws + 589824;          // 128*64          =    8192
    float* Vq   = ws + 598016;          // 128*512         =   65536
    float* P_c  = ws + 663552;          // 32*64           =    2048
    float* V_c  = ws + 665600;          // 32*512          =   16384
    float* Ppre = ws + 681984;          // 32*3*64         =    6144
    float* Vpre = ws + 688128;          // 32*3*512        =   49152
    float* S0c  = ws + 737280;          // 32*512          =   16384
    float* out  = (float*)d_out;

    hipLaunchKernelGGL(hippo_chunk_kernel,   dim3(NQ), dim3(128), 0, stream,
                       x_seq, Psub, Vsub, Pq, Vq);
    hipLaunchKernelGGL(hippo_merge_kernel,   dim3(32), dim3(512), 0, stream,
                       Pq, Vq, P_c, V_c, Ppre, Vpre);
    hipLaunchKernelGGL(hippo_compose_kernel, dim3(1),  dim3(512), 0, stream,
                       P_c, V_c, S0c);
    hipLaunchKernelGGL(kan_kernel, dim3(NROWS / 256), dim3(256), 0, stream,
                       x_seq, Psub, Vsub, S0c, Ppre, Vpre,
                       wb1, ws1, wb2, ws2, wb3, ws3, out);
}